// Round 3
// baseline (333.156 us; speedup 1.0000x reference)
//
#include <hip/hip_runtime.h>

#define N_NODES 100000
#define N_EDGES 1600000
#define F_IN    128
#define F_OUT   32
#define NB_SCAN ((N_NODES + 1023) / 1024)   // 98 scan blocks

__global__ void init_count_kernel(int* __restrict__ count) {
    int i = blockIdx.x * blockDim.x + threadIdx.x;
    if (i < N_NODES) count[i] = 0;
}

__global__ void hist_kernel(const int* __restrict__ ei, int* __restrict__ count) {
    int e = blockIdx.x * blockDim.x + threadIdx.x;
    if (e < N_EDGES) atomicAdd(&count[ei[N_EDGES + e]], 1);
}

__global__ void dinv_kernel(const int* __restrict__ count, float* __restrict__ dinv) {
    int i = blockIdx.x * blockDim.x + threadIdx.x;
    if (i < N_NODES) dinv[i] = rsqrtf((float)(count[i] + 1));  // +1 self loop
}

// per-block exclusive scan of count -> rowptr, block totals -> bsum
__global__ void scan1_kernel(const int* __restrict__ count, int* __restrict__ rowptr,
                             int* __restrict__ bsum) {
    __shared__ int lds[256];
    int tid = threadIdx.x;
    int base = blockIdx.x * 1024 + tid * 4;
    int v[4]; int s = 0;
#pragma unroll
    for (int k = 0; k < 4; ++k) {
        v[k] = (base + k < N_NODES) ? count[base + k] : 0;
        s += v[k];
    }
    lds[tid] = s;
    __syncthreads();
    for (int off = 1; off < 256; off <<= 1) {
        int t = (tid >= off) ? lds[tid - off] : 0;
        __syncthreads();
        lds[tid] += t;
        __syncthreads();
    }
    int run = lds[tid] - s;  // exclusive prefix of this thread's chunk
    if (tid == 255) bsum[blockIdx.x] = lds[255];
#pragma unroll
    for (int k = 0; k < 4; ++k) {
        if (base + k < N_NODES) { rowptr[base + k] = run; run += v[k]; }
    }
}

// exclusive scan of the 98 block sums, in place (single block)
__global__ void scan2_kernel(int* __restrict__ bsum) {
    __shared__ int lds[128];
    int tid = threadIdx.x;
    int v = (tid < NB_SCAN) ? bsum[tid] : 0;
    lds[tid] = v;
    __syncthreads();
    for (int off = 1; off < 128; off <<= 1) {
        int t = (tid >= off) ? lds[tid - off] : 0;
        __syncthreads();
        lds[tid] += t;
        __syncthreads();
    }
    if (tid < NB_SCAN) bsum[tid] = lds[tid] - v;
}

// add block offsets; also init cursor (= count buffer, reused) and rowptr[N]
__global__ void scan3_kernel(int* __restrict__ rowptr, const int* __restrict__ bsum,
                             int* __restrict__ cursor) {
    int i = blockIdx.x * blockDim.x + threadIdx.x;
    if (i < N_NODES) {
        int r = rowptr[i] + bsum[i >> 10];
        rowptr[i] = r;
        cursor[i] = r;
    }
    if (i == 0) rowptr[N_NODES] = N_EDGES;
}

// bucket edges by dst: ssrc[pos] = src
__global__ void scatter_sort_kernel(const int* __restrict__ ei, int* __restrict__ cursor,
                                    int* __restrict__ ssrc) {
    int e = blockIdx.x * blockDim.x + threadIdx.x;
    if (e < N_EDGES) {
        int s = ei[e];
        int d = ei[N_EDGES + e];
        int p = atomicAdd(&cursor[d], 1);
        ssrc[p] = s;
    }
}

// h = x @ W ; 32 lanes share a row, W staged in LDS
__global__ void matmul_kernel(const float* __restrict__ x, const float* __restrict__ W,
                              float* __restrict__ h) {
    __shared__ float Ws[F_IN * F_OUT];  // 16 KB
    for (int t = threadIdx.x; t < F_IN * F_OUT; t += blockDim.x) Ws[t] = W[t];
    __syncthreads();
    int idx = blockIdx.x * blockDim.x + threadIdx.x;
    int row = idx >> 5;
    int col = idx & 31;
    if (row < N_NODES) {
        const float* xr = x + (size_t)row * F_IN;
        float acc = 0.0f;
#pragma unroll
        for (int k = 0; k < F_IN; ++k) acc += xr[k] * Ws[k * F_OUT + col];
        h[(size_t)row * F_OUT + col] = acc;
    }
}

// one wave per node; lanes 0-31 / 32-63 process alternating CSR edges
__global__ void aggregate_kernel(const int* __restrict__ rowptr, const int* __restrict__ ssrc,
                                 const float* __restrict__ h, const float* __restrict__ dinv,
                                 const float* __restrict__ b, float* __restrict__ out) {
    int wid = (blockIdx.x * blockDim.x + threadIdx.x) >> 6;  // node id
    int lane = threadIdx.x & 63;
    if (wid >= N_NODES) return;
    int j = lane & 31;
    int half = lane >> 5;
    int beg = rowptr[wid];
    int end = rowptr[wid + 1];
    float acc = 0.0f;
    int p = beg + half;
    for (; p + 2 < end; p += 4) {
        int s0 = ssrc[p];
        int s1 = ssrc[p + 2];
        acc += h[(size_t)s0 * F_OUT + j] * dinv[s0];
        acc += h[(size_t)s1 * F_OUT + j] * dinv[s1];
    }
    if (p < end) {
        int s0 = ssrc[p];
        acc += h[(size_t)s0 * F_OUT + j] * dinv[s0];
    }
    acc += __shfl_xor(acc, 32, 64);  // combine the two halves
    if (half == 0) {
        float dv = dinv[wid];
        float self = h[(size_t)wid * F_OUT + j] * dv;
        out[(size_t)wid * F_OUT + j] = b[j] + dv * (acc + self);
    }
}

extern "C" void kernel_launch(void* const* d_in, const int* in_sizes, int n_in,
                              void* d_out, int out_size, void* d_ws, size_t ws_size,
                              hipStream_t stream) {
    const float* x  = (const float*)d_in[0];
    const int*   ei = (const int*)d_in[1];   // int32 on device
    const float* W  = (const float*)d_in[2];
    const float* b  = (const float*)d_in[3];
    float* out = (float*)d_out;

    int*   count  = (int*)d_ws;                       // N_NODES (reused as cursor)
    float* dinv   = (float*)(count + N_NODES);        // N_NODES
    int*   rowptr = (int*)(dinv + N_NODES);           // N_NODES + 1
    int*   bsum   = rowptr + N_NODES + 1;             // NB_SCAN
    int*   ssrc   = bsum + ((NB_SCAN + 3) & ~3);      // N_EDGES
    float* h      = (float*)(ssrc + N_EDGES);         // N_NODES * F_OUT

    const int B = 256;
    const int gN = (N_NODES + B - 1) / B;             // 391
    const int gE = (N_EDGES + B - 1) / B;             // 6250

    init_count_kernel<<<gN, B, 0, stream>>>(count);
    hist_kernel<<<gE, B, 0, stream>>>(ei, count);
    dinv_kernel<<<gN, B, 0, stream>>>(count, dinv);

    scan1_kernel<<<NB_SCAN, B, 0, stream>>>(count, rowptr, bsum);
    scan2_kernel<<<1, 128, 0, stream>>>(bsum);
    scan3_kernel<<<gN, B, 0, stream>>>(rowptr, bsum, count /*cursor*/);

    scatter_sort_kernel<<<gE, B, 0, stream>>>(ei, count /*cursor*/, ssrc);

    long long hw = (long long)N_NODES * F_OUT;        // 3.2M threads
    matmul_kernel<<<(int)((hw + B - 1) / B), B, 0, stream>>>(x, W, h);

    long long aw = (long long)N_NODES * 64;           // one wave per node
    aggregate_kernel<<<(int)((aw + B - 1) / B), B, 0, stream>>>(rowptr, ssrc, h, dinv, b, out);
}